// Round 13
// baseline (32018.613 us; speedup 1.0000x reference)
//
#include <hip/hip_runtime.h>

constexpr int kB = 64;
constexpr int kT = 1024;
constexpr int kC = 128;
constexpr int kH = 512;

constexpr int kWgPerGrp = 32;   // wgs per group (16 cols each)
constexpr int kRows     = 2;    // batches per group
constexpr int kHStride  = 652;  // hbuf row: 512 h + 128 x + 12 pad floats

#define SCOPE_AGENT __HIP_MEMORY_SCOPE_AGENT

__device__ __forceinline__ float sigmoidf_(float v) {
    return 1.0f / (1.0f + __expf(-v));
}

__device__ __forceinline__ void fma4_(float& a, const float4 h, const float4 w) {
    a = fmaf(h.x, w.x, a);
    a = fmaf(h.y, w.y, a);
    a = fmaf(h.z, w.z, a);
    a = fmaf(h.w, w.w, a);
}

// Persistent GRU. 1024 wgs x 256 threads, 4 wgs/CU (5.2KB LDS, <=128 VGPR via
// launch_bounds). 32 groups x 32 wgs.
// Mapping (R13): grp = (wg&7)*4 + ((wg>>8)&3), jb = (wg>>3)&31.
//  - group XCD-clustered: all wgs of a group share wg&7 (L2 locality).
//  - co-resident set {k, k+256, k+512, k+768} (breadth-first dispatch) lands
//    in 4 DIFFERENT independent groups -> 4 anti-phased chains per CU; the CU
//    only idles if all four groups are in their barrier chain simultaneously.
// Correctness does NOT depend on placement. Group g owns batches [g*2,+2);
// wg owns output columns [jb*16,+16).
// h-exchange through hs_out (proven): finishers publish relaxed agent-scope
// atomic stores (MALL-visible); consumers stage hs_out[:, t-1, :] with plain
// coalesced float4 loads — fresh addresses every step, no stale-cache risk.
// Step pipeline (R12-proven order):
//   1. issue h staging loads  2. x-part FMAs (covers 1)  3. LDS-write h; sync
//   4. issue x(t+1) load      5. h-part FMAs  6. reduce (covers 4)
//   7. write x(t+1) LDS       8. finish+publish  9. flag barrier
// R13 reduction (20 shfl vs 36): scatter row(xor8) -> jj(xor4) -> gate-pair
// (xor2) -> gate(xor1), K-butterfly xor16; lane s holds gate (s&3) for
// (row=(s>>3)&1, jj=(s>>2)&1); 4 index-shfls gather gates into finisher
// lanes (s&3==0, s<16).
__global__ __launch_bounds__(256, 4)
void gru_seq_kernel(const float* __restrict__ x,
                    const float* __restrict__ h0,
                    const float* __restrict__ w_ih,
                    const float* __restrict__ w_hh,
                    const float* __restrict__ b_ih,
                    const float* __restrict__ b_hh,
                    float* __restrict__ hs_out,   // d_out, [B,T,H]; also h-exchange
                    float* __restrict__ h_final,  // d_out + B*T*H
                    unsigned* __restrict__ flags) // d_ws: 32 x 32 uints
{
    const int wg  = blockIdx.x;
    const int grp = (wg & 7) * 4 + ((wg >> 8) & 3);   // 0..31
    const int jb  = (wg >> 3) & 31;                   // 0..31
    const int tid = threadIdx.x;
    const int jp  = tid >> 5;                   // 0..7 (j-pair)
    const int s   = tid & 31;                   // K-slice (lane bits 0-4)
    const int lane = tid & 63;
    const int b0  = grp * kRows;

    __shared__ float hbuf[kRows][kHStride];     // 5,216 B ([h | x] per row)

    // ---- one-time weight loads into REGISTERS ----
    const float4* w_hh4 = (const float4*)w_hh;
    const float4* w_ih4 = (const float4*)w_ih;
    float4 whR[4][3][2];   // [m][gate][jj]
    #pragma unroll
    for (int m = 0; m < 4; ++m)
        #pragma unroll
        for (int g = 0; g < 3; ++g)
            #pragma unroll
            for (int jj = 0; jj < 2; ++jj)
                whR[m][g][jj] =
                    w_hh4[((size_t)(g * kH + jb * 16 + jp * 2 + jj)) * (kH / 4)
                          + s + 32 * m];
    float4 wiR[3][2];      // [gate][jj] at x-f4 = s
    #pragma unroll
    for (int g = 0; g < 3; ++g)
        #pragma unroll
        for (int jj = 0; jj < 2; ++jj)
            wiR[g][jj] =
                w_ih4[((size_t)(g * kH + jb * 16 + jp * 2 + jj)) * (kC / 4) + s];

    // biases for this thread's finish output (finishers: s&3==0, s<16)
    const int jg_f = jb * 16 + jp * 2 + ((s >> 2) & 1);
    const float brz = b_ih[jg_f]          + b_hh[jg_f];
    const float bzz = b_ih[kH + jg_f]     + b_hh[kH + jg_f];
    const float bxn = b_ih[2 * kH + jg_f];
    const float bhn = b_hh[2 * kH + jg_f];

    unsigned* myflag = flags + grp * kWgPerGrp + jb;
    const unsigned* pollflag = flags + grp * kWgPerGrp + (tid & 31);

    // all-report barrier: store own epoch flag, lanes tid<32 poll all 32
    auto group_barrier = [&](unsigned e) {
        __syncthreads();   // vmcnt(0) drain: prior (atomic) stores MALL-visible
        if (tid < kWgPerGrp) {
            if (tid == 0)
                __hip_atomic_store(myflag, e, __ATOMIC_RELAXED, SCOPE_AGENT);
            unsigned v;
            do {
                v = __hip_atomic_load(pollflag, __ATOMIC_RELAXED, SCOPE_AGENT);
            } while (__any((int)(v < e)));
        }
        __syncthreads();
    };

    // ---- prologue: stage h0 and x(0) into LDS ----
    {   // 2 rows x 128 f4 = 256 f4, one per thread
        const int row = tid >> 7;
        const int f4  = tid & 127;
        *(float4*)&hbuf[row][f4 * 4] =
            *(const float4*)&h0[(size_t)(b0 + row) * kH + f4 * 4];
    }
    if (tid < 64) {
        const int row = tid >> 5;
        const int f4i = tid & 31;
        *(float4*)&hbuf[row][512 + f4i * 4] =
            *(const float4*)&x[((size_t)(b0 + row) * kT + 0) * kC + f4i * 4];
    }
    __syncthreads();

    const int st_row = tid >> 7;     // staging row/col for this thread
    const int st_f4  = tid & 127;

    for (int t = 0; t < kT; ++t) {
        // ---- (1) issue h staging load (plain coalesced, fresh address) ----
        float4 hv0;
        if (t > 0) {
            hv0 = *(const float4*)
                &hs_out[((size_t)(b0 + st_row) * kT + (t - 1)) * kH + st_f4 * 4];
        }

        // ---- (2) x-part FMAs (h-independent; covers the load's latency) ----
        float acc[4][2][2];
        #pragma unroll
        for (int g = 0; g < 4; ++g)
            #pragma unroll
            for (int i = 0; i < 2; ++i) {
                acc[g][i][0] = 0.f; acc[g][i][1] = 0.f;
            }
        {
            float4 x4v[2];
            #pragma unroll
            for (int i = 0; i < 2; ++i)
                x4v[i] = *(const float4*)(&hbuf[i][512 + s * 4]);
            #pragma unroll
            for (int g = 0; g < 3; ++g) {
                const int ga = (g == 2) ? 3 : g;   // x-side n -> acc[3]
                #pragma unroll
                for (int jj = 0; jj < 2; ++jj) {
                    const float4 w4 = wiR[g][jj];
                    #pragma unroll
                    for (int i = 0; i < 2; ++i)
                        fma4_(acc[ga][i][jj], x4v[i], w4);
                }
            }
        }

        // ---- (3) LDS-write staged h; sync ----
        if (t > 0) {
            *(float4*)&hbuf[st_row][st_f4 * 4] = hv0;
        }
        __syncthreads();   // staging visible; prior x-section reads done

        // ---- (4) issue x(t+1) load (latency hidden under h-part+reduce) ----
        float4 xnext;
        const bool do_x = (t + 1 < kT) && (tid < 64);
        if (do_x) {
            const int row = tid >> 5;
            const int f4i = tid & 31;
            xnext = *(const float4*)
                &x[((size_t)(b0 + row) * kT + (t + 1)) * kC + f4i * 4];
        }

        // ---- (5) h-part FMAs ----
        const float* hbase = &hbuf[0][s * 4];
        #pragma unroll
        for (int m = 0; m < 4; ++m) {         // h-k4 = s + 32m
            const int off = m * 128;
            float4 h4[2];
            #pragma unroll
            for (int i = 0; i < 2; ++i)
                h4[i] = *(const float4*)(hbase + i * kHStride + off);
            #pragma unroll
            for (int g = 0; g < 3; ++g)
                #pragma unroll
                for (int jj = 0; jj < 2; ++jj) {
                    const float4 w4 = whR[m][g][jj];
                    #pragma unroll
                    for (int i = 0; i < 2; ++i)
                        fma4_(acc[g][i][jj], h4[i], w4);
                }
        }

        // ---- (6) gate-scatter reduce: 16 shfl + 4 gather shfl ----
        const int  b3 = (s >> 3) & 1;   // row owner
        const int  b2 = (s >> 2) & 1;   // jj owner
        const int  b1 = (s >> 1) & 1;   // gate-pair owner
        const int  b0b = s & 1;         // gate-within-pair owner

        float A[4][2];                  // [gate][jj] after row scatter
        #pragma unroll
        for (int g = 0; g < 4; ++g)
            #pragma unroll
            for (int jj = 0; jj < 2; ++jj)
                A[g][jj] = acc[g][b3][jj] + __shfl_xor(acc[g][b3 ^ 1][jj], 8);
        float Bv[4];                    // [gate] after jj scatter
        #pragma unroll
        for (int g = 0; g < 4; ++g)
            Bv[g] = A[g][b2] + __shfl_xor(A[g][b2 ^ 1], 4);
        float Cv[2];                    // [gate within pair] after pair scatter
        #pragma unroll
        for (int k = 0; k < 2; ++k)
            Cv[k] = Bv[b1 * 2 + k] + __shfl_xor(Bv[(b1 ^ 1) * 2 + k], 2);
        float D = Cv[b0b] + __shfl_xor(Cv[b0b ^ 1], 1);   // gate scatter
        D += __shfl_xor(D, 16);                           // K-half butterfly
        // gather 4 gates into each lane's own (row,jj) quad base
        float Dv[4];
        #pragma unroll
        for (int g = 0; g < 4; ++g)
            Dv[g] = __shfl(D, (lane & 60) | g);

        // ---- (7) write x(t+1) into x-section (all waves passed sync-3) ----
        if (do_x) {
            const int row = tid >> 5;
            const int f4i = tid & 31;
            *(float4*)&hbuf[row][512 + f4i * 4] = xnext;
        }

        // ---- (8) finish + publish (lanes s&3==0, s<16) ----
        if ((s & 3) == 0 && s < 16) {
            const int   row  = (s >> 3) & 1;
            const int   bg   = b0 + row;
            const float rg   = sigmoidf_(Dv[0] + brz);
            const float zg   = sigmoidf_(Dv[1] + bzz);
            const float ng   = tanhf(Dv[3] + bxn + rg * (Dv[2] + bhn));
            const float hold = hbuf[row][jg_f];
            const float hnew = (1.f - zg) * ng + zg * hold;

            __hip_atomic_store(&hs_out[((size_t)bg * kT + t) * kH + jg_f], hnew,
                               __ATOMIC_RELAXED, SCOPE_AGENT);
            if (t == kT - 1) h_final[(size_t)bg * kH + jg_f] = hnew;
        }

        // ---- (9) barrier ----
        group_barrier((unsigned)(t + 1));
    }
}

// 32x32 tiled transpose: wpT[k][d] = w_post[d][k].  (R10-proven)
__global__ __launch_bounds__(256)
void wpt_kernel(const float* __restrict__ w_post, float* __restrict__ wpT)
{
    __shared__ float tile[32][33];
    const int bx = blockIdx.x & 15, by = blockIdx.x >> 4;
    const int tx = threadIdx.x & 31, ty = threadIdx.x >> 5;   // 32 x 8
    #pragma unroll
    for (int i = 0; i < 4; ++i)
        tile[ty + i * 8][tx] =
            w_post[(size_t)(by * 32 + ty + i * 8) * kH + bx * 32 + tx];
    __syncthreads();
    #pragma unroll
    for (int i = 0; i < 4; ++i)
        wpT[(size_t)(bx * 32 + ty + i * 8) * kH + by * 32 + tx] =
            tile[tx][ty + i * 8];
}

// In-place post projection, coalesced-w (R10-proven, ~FLOP-floor):
// out[b,t,:] = relu(hs[b,t,:] @ w_post^T + b_post), using wpT[k][d].
__global__ __launch_bounds__(128)
void post2_kernel(const float* __restrict__ wpT,
                  const float* __restrict__ b_post,
                  float* __restrict__ out)
{
    __shared__ float hb[16][kH];
    const int tid = threadIdx.x;
    const size_t row0 = (size_t)blockIdx.x * 16;

    const float4* src = (const float4*)(out + row0 * kH);
    float4* hb4 = (float4*)hb;
    for (int i = tid; i < 16 * kH / 4; i += 128) hb4[i] = src[i];
    __syncthreads();

    float4 acc[16];
    #pragma unroll
    for (int m = 0; m < 16; ++m) acc[m] = make_float4(0.f, 0.f, 0.f, 0.f);

    const float4* wT4 = (const float4*)wpT;
    for (int k4 = 0; k4 < kH / 4; ++k4) {
        const float4 w0 = wT4[(size_t)(k4 * 4 + 0) * 128 + tid];
        const float4 w1 = wT4[(size_t)(k4 * 4 + 1) * 128 + tid];
        const float4 w2 = wT4[(size_t)(k4 * 4 + 2) * 128 + tid];
        const float4 w3 = wT4[(size_t)(k4 * 4 + 3) * 128 + tid];
        #pragma unroll
        for (int m = 0; m < 16; ++m) {
            const float4 h4 = *(const float4*)&hb[m][k4 * 4];
            acc[m].x = fmaf(h4.x, w0.x, fmaf(h4.y, w1.x, fmaf(h4.z, w2.x, fmaf(h4.w, w3.x, acc[m].x))));
            acc[m].y = fmaf(h4.x, w0.y, fmaf(h4.y, w1.y, fmaf(h4.z, w2.y, fmaf(h4.w, w3.y, acc[m].y))));
            acc[m].z = fmaf(h4.x, w0.z, fmaf(h4.y, w1.z, fmaf(h4.z, w2.z, fmaf(h4.w, w3.z, acc[m].z))));
            acc[m].w = fmaf(h4.x, w0.w, fmaf(h4.y, w1.w, fmaf(h4.z, w2.w, fmaf(h4.w, w3.w, acc[m].w))));
        }
    }

    const float4 bp = *(const float4*)&b_post[tid * 4];
    #pragma unroll
    for (int m = 0; m < 16; ++m) {
        float4 r;
        r.x = fmaxf(acc[m].x + bp.x, 0.f);
        r.y = fmaxf(acc[m].y + bp.y, 0.f);
        r.z = fmaxf(acc[m].z + bp.z, 0.f);
        r.w = fmaxf(acc[m].w + bp.w, 0.f);
        *(float4*)&out[(row0 + m) * kH + tid * 4] = r;
    }
}

extern "C" void kernel_launch(void* const* d_in, const int* in_sizes, int n_in,
                              void* d_out, int out_size, void* d_ws, size_t ws_size,
                              hipStream_t stream) {
    const float* x      = (const float*)d_in[0];
    const float* h0     = (const float*)d_in[1];
    const float* w_ih   = (const float*)d_in[2];
    const float* w_hh   = (const float*)d_in[3];
    const float* b_ih   = (const float*)d_in[4];
    const float* b_hh   = (const float*)d_in[5];
    const float* w_post = (const float*)d_in[6];
    const float* b_post = (const float*)d_in[7];

    float* out     = (float*)d_out;
    float* h_final = out + (size_t)kB * kT * kH;

    unsigned* flags = (unsigned*)d_ws;                  // 32 x 32 uints = 4 KB
    float* wpT      = (float*)((char*)d_ws + 8192);     // 512 x 512 = 1 MB

    // flags must start at 0 every launch (d_ws is not re-poisoned per replay)
    hipMemsetAsync(d_ws, 0, 8192, stream);

    // transpose w_post (independent; stream-ordered before post2)
    wpt_kernel<<<dim3(256), dim3(256), 0, stream>>>(w_post, wpT);

    void* args[] = { (void*)&x, (void*)&h0, (void*)&w_ih, (void*)&w_hh,
                     (void*)&b_ih, (void*)&b_hh, (void*)&out, (void*)&h_final,
                     (void*)&flags };
    // Cooperative launch: 1024 wgs, 4/CU guaranteed by launch_bounds(256,4)
    // (VGPR capped at 128) + 5.2KB LDS. Fallback plain launch (last resort;
    // 4/CU co-resident in practice under the same resource budget).
    hipError_t err = hipLaunchCooperativeKernel((void*)gru_seq_kernel,
                                                dim3(1024), dim3(256),
                                                args, 0, stream);
    if (err != hipSuccess) {
        gru_seq_kernel<<<dim3(1024), dim3(256), 0, stream>>>(
            x, h0, w_ih, w_hh, b_ih, b_hh, out, h_final, flags);
    }

    post2_kernel<<<dim3(kB * kT / 16), dim3(128), 0, stream>>>(wpT, b_post, out);
}